// Round 11
// baseline (461.368 us; speedup 1.0000x reference)
//
#include <hip/hip_runtime.h>

typedef unsigned short u16;
typedef unsigned int u32;
typedef unsigned long long u64;
using short8 = __attribute__((ext_vector_type(8))) short;
using f32x4  = __attribute__((ext_vector_type(4))) float;

constexpr int Bb = 64, Ss = 1000, Dd = 128, Hh = 512;
constexpr int NN = Bb * Ss;           // 64000 nodes
constexpr int NSRC = Ss - 2;          // 998 kNN source nodes per batch

// ---------- helpers ----------
__device__ __forceinline__ float bf2f(u16 h) {
    u32 u = ((u32)h) << 16;
    return __builtin_bit_cast(float, u);
}
__device__ __forceinline__ u16 f2bf(float v) {  // RNE, finite inputs only
    u32 u = __builtin_bit_cast(u32, v);
    u32 r = (u + 0x7FFFu + ((u >> 16) & 1u)) >> 16;
    return (u16)r;
}
__device__ __forceinline__ float4 bf4(ushort4 v) {
    float4 r;
    r.x = bf2f(v.x); r.y = bf2f(v.y); r.z = bf2f(v.z); r.w = bf2f(v.w);
    return r;
}

// branchless insert of v into ascending bd[0..6] (drops the max).
__device__ __forceinline__ void ins7(float (&bd)[7], float v) {
#pragma unroll
    for (int k = 6; k >= 1; --k)
        bd[k] = __builtin_amdgcn_fmed3f(v, bd[k - 1], bd[k]);
    bd[0] = fminf(v, bd[0]);
}

// ---------- 1) kNN: approx-d2 phase 1 (widened threshold) + exact (d,j) re-rank ----------
// Phase 1 d2' = Ri+Rj-2xi*xj-2yi*yj (3 VALU); |d2'-d2_ref| <= ~2e-6 absolute,
// threshold widened +8e-6 >= 2E so all true top-7 pass the prefilter.
// Phase 2 prefilters with d2', recomputes the EXACT reference d2/sqrt inside the
// rare branch; final select of 7 smallest (d,j) u64 keys == bit-exact lax.top_k.
__global__ __launch_bounds__(256) void knn_kernel(const float* __restrict__ inputs,
                                                  u16* __restrict__ knn,
                                                  int* __restrict__ indeg) {
    __shared__ float2 pts[Ss];
    __shared__ float  nrm[Ss];
    __shared__ float  mg[32][56];
    __shared__ u64    lst[32][24];
    __shared__ int    cnt[32];
    __shared__ float  thr[32];

    int b = blockIdx.x;
    const float* base = inputs + (size_t)b * Ss * 2;
    for (int t = threadIdx.x; t < Ss; t += 256) {
        float2 p;
        p.x = base[2 * t];
        p.y = base[2 * t + 1];
        pts[t] = p;
        nrm[t] = p.x * p.x + p.y * p.y;     // approx path, any rounding
    }
    __syncthreads();

    int tid = threadIdx.x;
    int ln = tid >> 3;                  // local node 0..31
    int part = tid & 7;                 // candidate eighth 0..7
    int i = 2 + blockIdx.y * 32 + ln;
    bool valid = (i < Ss);
    int j0 = part * 125, j1 = j0 + 125;
    float xi = 0.f, yi = 0.f, Ri = 0.f;
    if (valid) { xi = pts[i].x; yi = pts[i].y; Ri = nrm[i]; }
    float m2x = -2.0f * xi, m2y = -2.0f * yi;
    const float INF = __builtin_inff();

    // ---- phase 1: 7-smallest approx d2 via med3 network ----
    if (valid) {
        float bd[7];
#pragma unroll
        for (int k = 0; k < 7; ++k) bd[k] = INF;
        for (int j = j0; j < j1; ++j) {
            float2 p = pts[j];
            float d2 = fmaf(p.x, m2x, fmaf(p.y, m2y, Ri + nrm[j]));
            d2 = (j == i) ? INF : d2;                 // exclude self
            ins7(bd, d2);
        }
#pragma unroll
        for (int k = 0; k < 7; ++k) mg[ln][part * 7 + k] = bd[k];
    }
    __syncthreads();

    // ---- merge 56 -> tau2'; widened threshold covers approx error ----
    if (part == 0 && valid) {
        float m[7];
#pragma unroll
        for (int k = 0; k < 7; ++k) m[k] = INF;
        for (int t = 0; t < 56; ++t) ins7(m, mg[ln][t]);
        thr[ln] = m[6] + 8e-6f;                        // >= exact tau2 (E<=2e-6)
        cnt[ln] = 0;
    }
    __syncthreads();

    // ---- phase 2: approx prefilter, exact (d, j) keys in rare branch ----
    if (valid) {
        float T = thr[ln];
        for (int j = j0; j < j1; ++j) {
            float2 p = pts[j];
            float d2a = fmaf(p.x, m2x, fmaf(p.y, m2y, Ri + nrm[j]));
            d2a = (j == i) ? INF : d2a;
            if (d2a <= T) {
                float dx = __fsub_rn(xi, p.x);         // exact fp32 RN mirror
                float dy = __fsub_rn(yi, p.y);
                float d2 = __fadd_rn(__fmul_rn(dx, dx), __fmul_rn(dy, dy));
                float d = __fsqrt_rn(d2);
                u64 key = (((u64)__builtin_bit_cast(u32, d)) << 32) | (u32)j;
                int p2 = atomicAdd(&cnt[ln], 1);
                if (p2 < 24) lst[ln][p2] = key;
            }
        }
    }
    __syncthreads();

    // ---- final: select 7 smallest (d, j) keys -> knn + indeg ----
    if (part == 0 && valid) {
        int c = cnt[ln]; if (c > 24) c = 24;           // c >= 7 by construction
        u16* kp = knn + ((size_t)b * NSRC + (i - 2)) * 7;
#pragma unroll
        for (int k = 0; k < 7; ++k) {
            u64 best = ~0ULL; int bp = -1;
            for (int t = 0; t < c; ++t) {
                u64 v = lst[ln][t];
                if (v < best) { best = v; bp = t; }
            }
            int j = 0;
            if (bp >= 0) { lst[ln][bp] = ~0ULL; j = (int)(u32)best; }
            kp[k] = (u16)j;
            if (j >= 2) atomicAdd(&indeg[b * Ss + j], 1);
        }
    }
}

// ---------- 2) degree -> dinv ----------
__global__ void deg_dinv_kernel(const int* __restrict__ indeg, float* __restrict__ dinv) {
    int n = blockIdx.x * 256 + threadIdx.x;
    if (n >= NN) return;
    int i = n % Ss;
    float deg = (i == 0) ? 1.0f : (i == 1) ? (float)(Ss - 1) : (float)(indeg[n] + 2);
    dinv[n] = 1.0f / __fsqrt_rn(deg);
}

// ---------- 3) coalesced 3-phase scan: indeg -> CSR offsets ----------
__global__ __launch_bounds__(1024) void scan1_kernel(const int* __restrict__ indeg,
                                                     int* __restrict__ offs,
                                                     int* __restrict__ bsum) {
    __shared__ int sh[1024];
    int t = threadIdx.x;
    int idx = blockIdx.x * 1024 + t;
    int v = (idx < NN) ? indeg[idx] : 0;
    sh[t] = v;
    __syncthreads();
    for (int off = 1; off < 1024; off <<= 1) {
        int u = (t >= off) ? sh[t - off] : 0;
        __syncthreads();
        sh[t] += u;
        __syncthreads();
    }
    if (idx < NN) offs[idx] = sh[t] - v;            // exclusive prefix
    if (t == 1023) bsum[blockIdx.x] = sh[1023];
}

__global__ void scan2_kernel(int* __restrict__ bsum) {
    if (threadIdx.x == 0) {
        int run = 0;
        for (int k = 0; k < 63; ++k) { int v = bsum[k]; bsum[k] = run; run += v; }
        bsum[63] = run;
    }
}

__global__ __launch_bounds__(1024) void scan3_kernel(int* __restrict__ offs,
                                                     const int* __restrict__ bsum) {
    int idx = blockIdx.x * 1024 + threadIdx.x;
    if (idx < NN) offs[idx] += bsum[blockIdx.x];
    if (idx == 0) offs[NN] = bsum[63];
}

// ---------- 4) scatter reverse adjacency ----------
__global__ __launch_bounds__(256) void fill_rev_kernel(const u16* __restrict__ knn,
                                                       const int* __restrict__ offs,
                                                       int* __restrict__ cursor,
                                                       u16* __restrict__ rev) {
    if (threadIdx.x >= 250) return;
    int b = blockIdx.x;
    int i = 2 + blockIdx.y * 250 + threadIdx.x;
    if (i >= Ss) return;
    const u16* kp = knn + ((size_t)b * NSRC + (i - 2)) * 7;
#pragma unroll
    for (int k = 0; k < 7; ++k) {
        int d = kp[k];
        if (d >= 2) {
            int n = b * Ss + d;
            int p = atomicAdd(&cursor[n], 1);
            rev[offs[n] + p] = (u16)i;
        }
    }
}

// ---------- 5) embedding -> single bf16 ----------
__global__ __launch_bounds__(256) void embed_kernel(const float* __restrict__ inputs,
                                                    const float* __restrict__ scor,
                                                    const float* __restrict__ Wc,
                                                    const float* __restrict__ bc,
                                                    const float* __restrict__ Ws,
                                                    const float* __restrict__ bs,
                                                    u16* __restrict__ xbf) {
    int gid = blockIdx.x * 256 + threadIdx.x;
    if (gid >= NN * Dd) return;
    int n = gid >> 7, c = gid & 127;
    float i0 = inputs[2 * n], i1 = inputs[2 * n + 1], sc = scor[n];
    float t1 = i0 * Wc[c] + i1 * Wc[Dd + c] + bc[c];
    float t2 = sc * Ws[c] + bs[c];
    xbf[gid] = f2bf(t1 + t2);
}

// ---------- 6) weight transpose -> single bf16: Wt[n][k] = bf16(W[k][n]) ----------
__global__ void transp_kernel(const float* __restrict__ src,
                              u16* __restrict__ dst, int R, int C) {
    int gid = blockIdx.x * 256 + threadIdx.x;
    if (gid >= R * C) return;
    int r = gid / C, c = gid - r * C;
    dst[c * R + r] = f2bf(src[gid]);
}

// ---------- 7) MFMA GEMM: Y(bf16) = A(bf16) @ W(bf16)^T, 1-MFMA ----------
__global__ __launch_bounds__(256) void gemm_kernel(const u16* __restrict__ A,
                                                   const u16* __restrict__ W,
                                                   u16* __restrict__ Y,
                                                   int K, int Ncols) {
    __shared__ __align__(16) u16 lA[128][64];
    __shared__ __align__(16) u16 lW[128][64];

    int row0 = blockIdx.y * 128;
    int col0 = blockIdx.x * 128;
    int tid = threadIdx.x;
    int lane = tid & 63, wid = tid >> 6;
    int wm = (wid >> 1) * 64, wn = (wid & 1) * 64;
    int lanelo = lane & 15, quad = lane >> 4;

    f32x4 acc[4][4] = {};

    int scb = tid & 7;          // col-block (8 bf16 each) 0..7
    int sr  = tid >> 3;         // 0..31

    for (int k0 = 0; k0 < K; k0 += 64) {
#pragma unroll
        for (int rr = 0; rr < 4; ++rr) {
            int r = sr + rr * 32;
            uint4 va = *(const uint4*)(A + (size_t)(row0 + r) * K + k0 + scb * 8);
            *(uint4*)&lA[r][(scb ^ (r & 7)) * 8] = va;   // XOR swizzle
        }
#pragma unroll
        for (int rr = 0; rr < 4; ++rr) {
            int r = sr + rr * 32;
            uint4 vw = *(const uint4*)(W + (size_t)(col0 + r) * K + k0 + scb * 8);
            *(uint4*)&lW[r][(scb ^ (r & 7)) * 8] = vw;
        }
        __syncthreads();

#pragma unroll
        for (int kk = 0; kk < 64; kk += 32) {
            short8 af[4], bw[4];
            int cbb = (kk >> 3) + quad;
#pragma unroll
            for (int mt = 0; mt < 4; ++mt) {
                int r = wm + mt * 16 + lanelo;
                af[mt] = *(const short8*)&lA[r][((cbb ^ (r & 7))) * 8];
            }
#pragma unroll
            for (int nt = 0; nt < 4; ++nt) {
                int r = wn + nt * 16 + lanelo;
                bw[nt] = *(const short8*)&lW[r][((cbb ^ (r & 7))) * 8];
            }
#pragma unroll
            for (int mt = 0; mt < 4; ++mt)
#pragma unroll
                for (int nt = 0; nt < 4; ++nt)
                    acc[mt][nt] = __builtin_amdgcn_mfma_f32_16x16x32_bf16(
                        af[mt], bw[nt], acc[mt][nt], 0, 0, 0);
        }
        __syncthreads();
    }

#pragma unroll
    for (int mt = 0; mt < 4; ++mt)
#pragma unroll
        for (int nt = 0; nt < 4; ++nt)
#pragma unroll
            for (int r = 0; r < 4; ++r) {
                int row = row0 + wm + mt * 16 + quad * 4 + r;
                int col = col0 + wn + nt * 16 + lanelo;
                Y[(size_t)row * Ncols + col] = f2bf(acc[mt][nt][r]);
            }
}

// ---------- 7b) depot-1 partial sums ----------
__global__ __launch_bounds__(1024) void dep1_kernel(const u16* __restrict__ y,
                                                    const float* __restrict__ dinv,
                                                    float* __restrict__ dq,
                                                    int M) {
    int b = blockIdx.x;
    int qq = blockIdx.y;                 // quarter 0..3
    int co = blockIdx.z * 128;
    int tid = threadIdx.x;
    int c4 = tid & 31;
    int es = tid >> 5;
    int j0 = 2 + qq * 250;
    int j1 = j0 + 250; if (j1 > Ss) j1 = Ss;
    const u16* yb = y + (size_t)b * Ss * M + co + c4 * 4;
    const float* dv = dinv + b * Ss;
    float a0 = 0.f, a1 = 0.f, a2 = 0.f, a3 = 0.f;
    for (int j = j0 + es; j < j1; j += 32) {
        float w = dv[j];
        float4 u = bf4(*(const ushort4*)(yb + (size_t)j * M));
        a0 += u.x * w; a1 += u.y * w; a2 += u.z * w; a3 += u.w * w;
    }
    __shared__ float4 red[1024];
    float4 mv; mv.x = a0; mv.y = a1; mv.z = a2; mv.w = a3;
    red[tid] = mv;
    __syncthreads();
#pragma unroll
    for (int s = 16; s > 0; s >>= 1) {
        if (es < s) {
            float4 o = red[tid + (s << 5)];
            float4 m = red[tid];
            m.x += o.x; m.y += o.y; m.z += o.z; m.w += o.w;
            red[tid] = m;
        }
        __syncthreads();
    }
    if (es == 0)
        *(float4*)(dq + ((size_t)qq * Bb + b) * M + co + c4 * 4) = red[c4];
}

// ---------- 8) aggregation M=512 + bias + relu -> single bf16 ----------
__global__ __launch_bounds__(128) void agg512_kernel(const u16* __restrict__ y,
                                                     const float* __restrict__ dinv,
                                                     const int* __restrict__ offs,
                                                     const int* __restrict__ indeg,
                                                     const u16* __restrict__ rev,
                                                     const float* __restrict__ bias,
                                                     const float* __restrict__ dep1,
                                                     u16* __restrict__ oX) {
    int bx = blockIdx.x;
    int x = bx & 7, q = bx >> 3;
    int bb = q / 1000;
    int i = q - bb * 1000;
    int b = x + (bb << 3);
    int n = b * Ss + i;
    int nb = n - i;
    int tid = threadIdx.x, c = tid * 4;

    __shared__ int   sidx[128];
    __shared__ float sw[128];
    int cnt = 0, o = 0;
    if (i >= 2) { cnt = indeg[n]; o = offs[n]; }
    int cl = cnt < 128 ? cnt : 128;
    if (tid < cl) {
        int s = rev[o + tid];
        sidx[tid] = s;
        sw[tid] = dinv[nb + s];
    }
    __syncthreads();

    float a0 = 0.f, a1 = 0.f, a2 = 0.f, a3 = 0.f;
    if (i >= 2) {
        float w = dinv[nb];  // == 1.0 (deg[0]=1)
        float4 v = bf4(*(const ushort4*)(y + (size_t)nb * 512 + c));
        a0 = v.x * w; a1 = v.y * w; a2 = v.z * w; a3 = v.w * w;
        int e = 0;
        for (; e + 4 <= cl; e += 4) {
            int s0 = sidx[e], s1 = sidx[e + 1], s2 = sidx[e + 2], s3 = sidx[e + 3];
            float w0 = sw[e], w1 = sw[e + 1], w2 = sw[e + 2], w3 = sw[e + 3];
            float4 u0 = bf4(*(const ushort4*)(y + (size_t)(nb + s0) * 512 + c));
            float4 u1 = bf4(*(const ushort4*)(y + (size_t)(nb + s1) * 512 + c));
            float4 u2 = bf4(*(const ushort4*)(y + (size_t)(nb + s2) * 512 + c));
            float4 u3 = bf4(*(const ushort4*)(y + (size_t)(nb + s3) * 512 + c));
            a0 += u0.x * w0 + u1.x * w1 + u2.x * w2 + u3.x * w3;
            a1 += u0.y * w0 + u1.y * w1 + u2.y * w2 + u3.y * w3;
            a2 += u0.z * w0 + u1.z * w1 + u2.z * w2 + u3.z * w3;
            a3 += u0.w * w0 + u1.w * w1 + u2.w * w2 + u3.w * w3;
        }
        for (; e < cl; ++e) {
            int s = sidx[e]; float ww = sw[e];
            float4 u = bf4(*(const ushort4*)(y + (size_t)(nb + s) * 512 + c));
            a0 += u.x * ww; a1 += u.y * ww; a2 += u.z * ww; a3 += u.w * ww;
        }
        for (int e2 = 128; e2 < cnt; ++e2) {   // safety fallback (never in practice)
            int s = rev[o + e2]; float ww = dinv[nb + s];
            float4 u = bf4(*(const ushort4*)(y + (size_t)(nb + s) * 512 + c));
            a0 += u.x * ww; a1 += u.y * ww; a2 += u.z * ww; a3 += u.w * ww;
        }
    } else if (i == 1) {
        const float* dp = dep1 + (size_t)b * 512 + c;
#pragma unroll
        for (int qq = 0; qq < 4; ++qq) {
            float4 v = *(const float4*)(dp + (size_t)qq * Bb * 512);
            a0 += v.x; a1 += v.y; a2 += v.z; a3 += v.w;
        }
    }
    float dn = dinv[n], sn = dn * dn;
    float4 vs = bf4(*(const ushort4*)(y + (size_t)n * 512 + c));
    float z0 = a0 * dn + vs.x * sn + bias[c];
    float z1 = a1 * dn + vs.y * sn + bias[c + 1];
    float z2 = a2 * dn + vs.z * sn + bias[c + 2];
    float z3 = a3 * dn + vs.w * sn + bias[c + 3];
    ushort4 hv;
    hv.x = f2bf(fmaxf(z0, 0.f));
    hv.y = f2bf(fmaxf(z1, 0.f));
    hv.z = f2bf(fmaxf(z2, 0.f));
    hv.w = f2bf(fmaxf(z3, 0.f));
    *(ushort4*)(oX + (size_t)n * 512 + c) = hv;
}

// ---------- 9) final aggregation M=128, no relu, fp32 out ----------
__global__ __launch_bounds__(128) void agg128f_kernel(const u16* __restrict__ y,
                                                      const float* __restrict__ dinv,
                                                      const int* __restrict__ offs,
                                                      const int* __restrict__ indeg,
                                                      const u16* __restrict__ rev,
                                                      const float* __restrict__ bias,
                                                      const float* __restrict__ dep1,
                                                      float* __restrict__ out) {
    int bx = blockIdx.x;
    int x = bx & 7, q = bx >> 3;
    int bb = q / 1000;
    int i = q - bb * 1000;
    int b = x + (bb << 3);
    int n = b * Ss + i;
    int nb = n - i;
    int tid = threadIdx.x, c = tid;

    __shared__ int   sidx[128];
    __shared__ float sw[128];
    int cnt = 0, o = 0;
    if (i >= 2) { cnt = indeg[n]; o = offs[n]; }
    int cl = cnt < 128 ? cnt : 128;
    if (tid < cl) {
        int s = rev[o + tid];
        sidx[tid] = s;
        sw[tid] = dinv[nb + s];
    }
    __syncthreads();

    float a = 0.f;
    if (i >= 2) {
        a = bf2f(y[(size_t)nb * 128 + c]) * dinv[nb];
        int e = 0;
        for (; e + 4 <= cl; e += 4) {
            int s0 = sidx[e], s1 = sidx[e + 1], s2 = sidx[e + 2], s3 = sidx[e + 3];
            float w0 = sw[e], w1 = sw[e + 1], w2 = sw[e + 2], w3 = sw[e + 3];
            float u0 = bf2f(y[(size_t)(nb + s0) * 128 + c]);
            float u1 = bf2f(y[(size_t)(nb + s1) * 128 + c]);
            float u2 = bf2f(y[(size_t)(nb + s2) * 128 + c]);
            float u3 = bf2f(y[(size_t)(nb + s3) * 128 + c]);
            a += u0 * w0 + u1 * w1 + u2 * w2 + u3 * w3;
        }
        for (; e < cl; ++e) a += bf2f(y[(size_t)(nb + sidx[e]) * 128 + c]) * sw[e];
        for (int e2 = 128; e2 < cnt; ++e2) {
            int s = rev[o + e2];
            a += bf2f(y[(size_t)(nb + s) * 128 + c]) * dinv[nb + s];
        }
    } else if (i == 1) {
#pragma unroll
        for (int qq = 0; qq < 4; ++qq)
            a += dep1[((size_t)qq * Bb + b) * 128 + c];
    }
    float dn = dinv[n];
    out[(size_t)n * 128 + c] = a * dn + bf2f(y[(size_t)n * 128 + c]) * (dn * dn) + bias[c];
}

// ---------- workspace layout (bytes); total ~134.9 MB ----------
constexpr size_t O_INDEG  = 0;                       // 256000
constexpr size_t O_CURSOR = 256000;                  // 256000
constexpr size_t O_OFFS   = 512000;                  // 256016
constexpr size_t O_DINV   = 768256;                  // 256000
constexpr size_t O_KNN    = 1024256;                 // 893824
constexpr size_t O_REV    = 1918080;                 // 893824
constexpr size_t O_WT0    = 2811904;                 // 512*128*2 = 131072
constexpr size_t O_WT1    = 2942976;                 // 512*512*2 = 524288
constexpr size_t O_WT2    = 3467264;                 // 128*512*2 = 131072
constexpr size_t O_X      = 3598336;                 // 64000*512*2 = 65536000 (bf16 acts)
constexpr size_t O_Y      = 69134336;                // 65536000 (bf16 y)
constexpr size_t O_DEP1A  = 134670336;               // 4*64*512*4 = 524288
constexpr size_t O_DEP1B  = 135194624;               // 4*64*128*4 = 131072
constexpr size_t O_BSUM   = 135325696;               // 256

extern "C" void kernel_launch(void* const* d_in, const int* in_sizes, int n_in,
                              void* d_out, int out_size, void* d_ws, size_t ws_size,
                              hipStream_t stream) {
    const float* inputs = (const float*)d_in[0];
    const float* scor   = (const float*)d_in[1];
    const float* Wc     = (const float*)d_in[2];
    const float* bc     = (const float*)d_in[3];
    const float* Ws     = (const float*)d_in[4];
    const float* bs     = (const float*)d_in[5];
    const float* W0     = (const float*)d_in[6];
    const float* b0     = (const float*)d_in[7];
    const float* W1     = (const float*)d_in[8];
    const float* b1     = (const float*)d_in[9];
    const float* W2     = (const float*)d_in[10];
    const float* b2     = (const float*)d_in[11];

    char* w = (char*)d_ws;
    int*   indeg  = (int*)(w + O_INDEG);
    int*   cursor = (int*)(w + O_CURSOR);
    int*   offs   = (int*)(w + O_OFFS);
    float* dinv   = (float*)(w + O_DINV);
    u16*   knn    = (u16*)(w + O_KNN);
    u16*   rev    = (u16*)(w + O_REV);
    u16*   wt0    = (u16*)(w + O_WT0);
    u16*   wt1    = (u16*)(w + O_WT1);
    u16*   wt2    = (u16*)(w + O_WT2);
    u16*   xbf    = (u16*)(w + O_X);
    u16*   ybf    = (u16*)(w + O_Y);
    float* dep1a  = (float*)(w + O_DEP1A);
    float* dep1b  = (float*)(w + O_DEP1B);
    int*   bsum   = (int*)(w + O_BSUM);

    hipMemsetAsync(w + O_INDEG, 0, 512000, stream);  // indeg + cursor

    knn_kernel<<<dim3(Bb, 32), 256, 0, stream>>>(inputs, knn, indeg);
    deg_dinv_kernel<<<250, 256, 0, stream>>>(indeg, dinv);
    scan1_kernel<<<63, 1024, 0, stream>>>(indeg, offs, bsum);
    scan2_kernel<<<1, 64, 0, stream>>>(bsum);
    scan3_kernel<<<63, 1024, 0, stream>>>(offs, bsum);
    fill_rev_kernel<<<dim3(Bb, 4), 256, 0, stream>>>(knn, offs, cursor, rev);

    embed_kernel<<<NN * Dd / 256, 256, 0, stream>>>(inputs, scor, Wc, bc, Ws, bs, xbf);

    transp_kernel<<<(Dd * Hh + 255) / 256, 256, 0, stream>>>(W0, wt0, Dd, Hh);
    transp_kernel<<<(Hh * Hh + 255) / 256, 256, 0, stream>>>(W1, wt1, Hh, Hh);
    transp_kernel<<<(Hh * Dd + 255) / 256, 256, 0, stream>>>(W2, wt2, Hh, Dd);

    // layer 0: [N,128] @ [128,512]
    gemm_kernel<<<dim3(Hh / 128, NN / 128), 256, 0, stream>>>(xbf, wt0, ybf, Dd, Hh);
    dep1_kernel<<<dim3(Bb, 4, 4), 1024, 0, stream>>>(ybf, dinv, dep1a, Hh);
    agg512_kernel<<<NN, 128, 0, stream>>>(ybf, dinv, offs, indeg, rev, b0, dep1a, xbf);
    // layer 1: [N,512] @ [512,512]
    gemm_kernel<<<dim3(Hh / 128, NN / 128), 256, 0, stream>>>(xbf, wt1, ybf, Hh, Hh);
    dep1_kernel<<<dim3(Bb, 4, 4), 1024, 0, stream>>>(ybf, dinv, dep1a, Hh);
    agg512_kernel<<<NN, 128, 0, stream>>>(ybf, dinv, offs, indeg, rev, b1, dep1a, xbf);
    // layer 2: [N,512] @ [512,128]
    gemm_kernel<<<dim3(Dd / 128, NN / 128), 256, 0, stream>>>(xbf, wt2, ybf, Hh, Dd);
    dep1_kernel<<<dim3(Bb, 4, 1), 1024, 0, stream>>>(ybf, dinv, dep1b, Dd);
    agg128f_kernel<<<NN, 128, 0, stream>>>(ybf, dinv, offs, indeg, rev, b2, dep1b, (float*)d_out);
}

// Round 12
// 451.611 us; speedup vs baseline: 1.0216x; 1.0216x over previous
//
#include <hip/hip_runtime.h>

typedef unsigned short u16;
typedef unsigned int u32;
typedef unsigned long long u64;
using short8 = __attribute__((ext_vector_type(8))) short;
using f32x4  = __attribute__((ext_vector_type(4))) float;

constexpr int Bb = 64, Ss = 1000, Dd = 128, Hh = 512;
constexpr int NN = Bb * Ss;           // 64000 nodes
constexpr int NSRC = Ss - 2;          // 998 kNN source nodes per batch

// ---------- helpers ----------
__device__ __forceinline__ float bf2f(u16 h) {
    u32 u = ((u32)h) << 16;
    return __builtin_bit_cast(float, u);
}
__device__ __forceinline__ u16 f2bf(float v) {  // RNE, finite inputs only
    u32 u = __builtin_bit_cast(u32, v);
    u32 r = (u + 0x7FFFu + ((u >> 16) & 1u)) >> 16;
    return (u16)r;
}
__device__ __forceinline__ float4 bf4(ushort4 v) {
    float4 r;
    r.x = bf2f(v.x); r.y = bf2f(v.y); r.z = bf2f(v.z); r.w = bf2f(v.w);
    return r;
}

// branchless insert of v into ascending bd[0..6] (drops the max).
__device__ __forceinline__ void ins7(float (&bd)[7], float v) {
#pragma unroll
    for (int k = 6; k >= 1; --k)
        bd[k] = __builtin_amdgcn_fmed3f(v, bd[k - 1], bd[k]);
    bd[0] = fminf(v, bd[0]);
}

// ---------- 1) kNN: approx-d2 phase 1 (widened threshold) + exact (d,j) re-rank ----------
__global__ __launch_bounds__(256) void knn_kernel(const float* __restrict__ inputs,
                                                  u16* __restrict__ knn,
                                                  int* __restrict__ indeg) {
    __shared__ float2 pts[Ss];
    __shared__ float  nrm[Ss];
    __shared__ float  mg[32][56];
    __shared__ u64    lst[32][24];
    __shared__ int    cnt[32];
    __shared__ float  thr[32];

    int b = blockIdx.x;
    const float* base = inputs + (size_t)b * Ss * 2;
    for (int t = threadIdx.x; t < Ss; t += 256) {
        float2 p;
        p.x = base[2 * t];
        p.y = base[2 * t + 1];
        pts[t] = p;
        nrm[t] = p.x * p.x + p.y * p.y;     // approx path, any rounding
    }
    __syncthreads();

    int tid = threadIdx.x;
    int ln = tid >> 3;                  // local node 0..31
    int part = tid & 7;                 // candidate eighth 0..7
    int i = 2 + blockIdx.y * 32 + ln;
    bool valid = (i < Ss);
    int j0 = part * 125, j1 = j0 + 125;
    float xi = 0.f, yi = 0.f, Ri = 0.f;
    if (valid) { xi = pts[i].x; yi = pts[i].y; Ri = nrm[i]; }
    float m2x = -2.0f * xi, m2y = -2.0f * yi;
    const float INF = __builtin_inff();

    // ---- phase 1: 7-smallest approx d2 via med3 network ----
    if (valid) {
        float bd[7];
#pragma unroll
        for (int k = 0; k < 7; ++k) bd[k] = INF;
        for (int j = j0; j < j1; ++j) {
            float2 p = pts[j];
            float d2 = fmaf(p.x, m2x, fmaf(p.y, m2y, Ri + nrm[j]));
            d2 = (j == i) ? INF : d2;                 // exclude self
            ins7(bd, d2);
        }
#pragma unroll
        for (int k = 0; k < 7; ++k) mg[ln][part * 7 + k] = bd[k];
    }
    __syncthreads();

    // ---- merge 56 -> tau2'; widened threshold covers approx error ----
    if (part == 0 && valid) {
        float m[7];
#pragma unroll
        for (int k = 0; k < 7; ++k) m[k] = INF;
        for (int t = 0; t < 56; ++t) ins7(m, mg[ln][t]);
        thr[ln] = m[6] + 8e-6f;                        // >= exact tau2 (E<=2e-6)
        cnt[ln] = 0;
    }
    __syncthreads();

    // ---- phase 2: approx prefilter, exact (d, j) keys in rare branch ----
    if (valid) {
        float T = thr[ln];
        for (int j = j0; j < j1; ++j) {
            float2 p = pts[j];
            float d2a = fmaf(p.x, m2x, fmaf(p.y, m2y, Ri + nrm[j]));
            d2a = (j == i) ? INF : d2a;
            if (d2a <= T) {
                float dx = __fsub_rn(xi, p.x);         // exact fp32 RN mirror
                float dy = __fsub_rn(yi, p.y);
                float d2 = __fadd_rn(__fmul_rn(dx, dx), __fmul_rn(dy, dy));
                float d = __fsqrt_rn(d2);
                u64 key = (((u64)__builtin_bit_cast(u32, d)) << 32) | (u32)j;
                int p2 = atomicAdd(&cnt[ln], 1);
                if (p2 < 24) lst[ln][p2] = key;
            }
        }
    }
    __syncthreads();

    // ---- final: select 7 smallest (d, j) keys -> knn + indeg ----
    if (part == 0 && valid) {
        int c = cnt[ln]; if (c > 24) c = 24;           // c >= 7 by construction
        u16* kp = knn + ((size_t)b * NSRC + (i - 2)) * 7;
#pragma unroll
        for (int k = 0; k < 7; ++k) {
            u64 best = ~0ULL; int bp = -1;
            for (int t = 0; t < c; ++t) {
                u64 v = lst[ln][t];
                if (v < best) { best = v; bp = t; }
            }
            int j = 0;
            if (bp >= 0) { lst[ln][bp] = ~0ULL; j = (int)(u32)best; }
            kp[k] = (u16)j;
            if (j >= 2) atomicAdd(&indeg[b * Ss + j], 1);
        }
    }
}

// ---------- 2) degree -> dinv ----------
__global__ void deg_dinv_kernel(const int* __restrict__ indeg, float* __restrict__ dinv) {
    int n = blockIdx.x * 256 + threadIdx.x;
    if (n >= NN) return;
    int i = n % Ss;
    float deg = (i == 0) ? 1.0f : (i == 1) ? (float)(Ss - 1) : (float)(indeg[n] + 2);
    dinv[n] = 1.0f / __fsqrt_rn(deg);
}

// ---------- 3) coalesced 3-phase scan: indeg -> CSR offsets ----------
__global__ __launch_bounds__(1024) void scan1_kernel(const int* __restrict__ indeg,
                                                     int* __restrict__ offs,
                                                     int* __restrict__ bsum) {
    __shared__ int sh[1024];
    int t = threadIdx.x;
    int idx = blockIdx.x * 1024 + t;
    int v = (idx < NN) ? indeg[idx] : 0;
    sh[t] = v;
    __syncthreads();
    for (int off = 1; off < 1024; off <<= 1) {
        int u = (t >= off) ? sh[t - off] : 0;
        __syncthreads();
        sh[t] += u;
        __syncthreads();
    }
    if (idx < NN) offs[idx] = sh[t] - v;            // exclusive prefix
    if (t == 1023) bsum[blockIdx.x] = sh[1023];
}

__global__ void scan2_kernel(int* __restrict__ bsum) {
    if (threadIdx.x == 0) {
        int run = 0;
        for (int k = 0; k < 63; ++k) { int v = bsum[k]; bsum[k] = run; run += v; }
        bsum[63] = run;
    }
}

__global__ __launch_bounds__(1024) void scan3_kernel(int* __restrict__ offs,
                                                     const int* __restrict__ bsum) {
    int idx = blockIdx.x * 1024 + threadIdx.x;
    if (idx < NN) offs[idx] += bsum[blockIdx.x];
    if (idx == 0) offs[NN] = bsum[63];
}

// ---------- 4) scatter reverse adjacency ----------
__global__ __launch_bounds__(256) void fill_rev_kernel(const u16* __restrict__ knn,
                                                       const int* __restrict__ offs,
                                                       int* __restrict__ cursor,
                                                       u16* __restrict__ rev) {
    if (threadIdx.x >= 250) return;
    int b = blockIdx.x;
    int i = 2 + blockIdx.y * 250 + threadIdx.x;
    if (i >= Ss) return;
    const u16* kp = knn + ((size_t)b * NSRC + (i - 2)) * 7;
#pragma unroll
    for (int k = 0; k < 7; ++k) {
        int d = kp[k];
        if (d >= 2) {
            int n = b * Ss + d;
            int p = atomicAdd(&cursor[n], 1);
            rev[offs[n] + p] = (u16)i;
        }
    }
}

// ---------- 5) layer-0 weight folding: A = [Wc0;Wc1;Ws;(bc+bs)] @ W0  (4 x 512 fp32) ----------
__global__ __launch_bounds__(512) void fuse0_kernel(const float* __restrict__ Wc,
                                                    const float* __restrict__ bc,
                                                    const float* __restrict__ Ws,
                                                    const float* __restrict__ bs,
                                                    const float* __restrict__ W0,
                                                    float* __restrict__ A) {
    int h = threadIdx.x;
    float a0 = 0.f, a1 = 0.f, a2 = 0.f, a3 = 0.f;
    for (int c = 0; c < Dd; ++c) {
        float w = W0[c * Hh + h];
        a0 += Wc[c] * w;
        a1 += Wc[Dd + c] * w;
        a2 += Ws[c] * w;
        a3 += (bc[c] + bs[c]) * w;
    }
    A[h] = a0; A[Hh + h] = a1; A[2 * Hh + h] = a2; A[3 * Hh + h] = a3;
}

// ---------- 5b) fused embed+gemm0: y0[n,h] = i0*A0 + i1*A1 + sc*A2 + A3 (bf16 out) ----------
__global__ __launch_bounds__(256) void gemm0f_kernel(const float* __restrict__ inputs,
                                                     const float* __restrict__ scor,
                                                     const float* __restrict__ A,
                                                     u16* __restrict__ Y) {
    int gid = blockIdx.x * 256 + threadIdx.x;       // NN*128 h-quads
    if (gid >= NN * 128) return;
    int n = gid >> 7, t = gid & 127;
    int h = t * 4;
    float i0 = inputs[2 * n], i1 = inputs[2 * n + 1], sc = scor[n];
    float4 a0 = *(const float4*)(A + h);
    float4 a1 = *(const float4*)(A + Hh + h);
    float4 a2 = *(const float4*)(A + 2 * Hh + h);
    float4 a3 = *(const float4*)(A + 3 * Hh + h);
    ushort4 o;
    o.x = f2bf(i0 * a0.x + i1 * a1.x + sc * a2.x + a3.x);
    o.y = f2bf(i0 * a0.y + i1 * a1.y + sc * a2.y + a3.y);
    o.z = f2bf(i0 * a0.z + i1 * a1.z + sc * a2.z + a3.z);
    o.w = f2bf(i0 * a0.w + i1 * a1.w + sc * a2.w + a3.w);
    *(ushort4*)(Y + (size_t)n * Hh + h) = o;
}

// ---------- 6) weight transpose -> single bf16: Wt[n][k] = bf16(W[k][n]) ----------
__global__ void transp_kernel(const float* __restrict__ src,
                              u16* __restrict__ dst, int R, int C) {
    int gid = blockIdx.x * 256 + threadIdx.x;
    if (gid >= R * C) return;
    int r = gid / C, c = gid - r * C;
    dst[c * R + r] = f2bf(src[gid]);
}

// ---------- 7) MFMA GEMM: Y(bf16) = A(bf16) @ W(bf16)^T, 1-MFMA ----------
__global__ __launch_bounds__(256) void gemm_kernel(const u16* __restrict__ A,
                                                   const u16* __restrict__ W,
                                                   u16* __restrict__ Y,
                                                   int K, int Ncols) {
    __shared__ __align__(16) u16 lA[128][64];
    __shared__ __align__(16) u16 lW[128][64];

    int row0 = blockIdx.y * 128;
    int col0 = blockIdx.x * 128;
    int tid = threadIdx.x;
    int lane = tid & 63, wid = tid >> 6;
    int wm = (wid >> 1) * 64, wn = (wid & 1) * 64;
    int lanelo = lane & 15, quad = lane >> 4;

    f32x4 acc[4][4] = {};

    int scb = tid & 7;          // col-block (8 bf16 each) 0..7
    int sr  = tid >> 3;         // 0..31

    for (int k0 = 0; k0 < K; k0 += 64) {
#pragma unroll
        for (int rr = 0; rr < 4; ++rr) {
            int r = sr + rr * 32;
            uint4 va = *(const uint4*)(A + (size_t)(row0 + r) * K + k0 + scb * 8);
            *(uint4*)&lA[r][(scb ^ (r & 7)) * 8] = va;   // XOR swizzle
        }
#pragma unroll
        for (int rr = 0; rr < 4; ++rr) {
            int r = sr + rr * 32;
            uint4 vw = *(const uint4*)(W + (size_t)(col0 + r) * K + k0 + scb * 8);
            *(uint4*)&lW[r][(scb ^ (r & 7)) * 8] = vw;
        }
        __syncthreads();

#pragma unroll
        for (int kk = 0; kk < 64; kk += 32) {
            short8 af[4], bw[4];
            int cbb = (kk >> 3) + quad;
#pragma unroll
            for (int mt = 0; mt < 4; ++mt) {
                int r = wm + mt * 16 + lanelo;
                af[mt] = *(const short8*)&lA[r][((cbb ^ (r & 7))) * 8];
            }
#pragma unroll
            for (int nt = 0; nt < 4; ++nt) {
                int r = wn + nt * 16 + lanelo;
                bw[nt] = *(const short8*)&lW[r][((cbb ^ (r & 7))) * 8];
            }
#pragma unroll
            for (int mt = 0; mt < 4; ++mt)
#pragma unroll
                for (int nt = 0; nt < 4; ++nt)
                    acc[mt][nt] = __builtin_amdgcn_mfma_f32_16x16x32_bf16(
                        af[mt], bw[nt], acc[mt][nt], 0, 0, 0);
        }
        __syncthreads();
    }

#pragma unroll
    for (int mt = 0; mt < 4; ++mt)
#pragma unroll
        for (int nt = 0; nt < 4; ++nt)
#pragma unroll
            for (int r = 0; r < 4; ++r) {
                int row = row0 + wm + mt * 16 + quad * 4 + r;
                int col = col0 + wn + nt * 16 + lanelo;
                Y[(size_t)row * Ncols + col] = f2bf(acc[mt][nt][r]);
            }
}

// ---------- 7b) depot-1 partial sums ----------
__global__ __launch_bounds__(1024) void dep1_kernel(const u16* __restrict__ y,
                                                    const float* __restrict__ dinv,
                                                    float* __restrict__ dq,
                                                    int M) {
    int b = blockIdx.x;
    int qq = blockIdx.y;                 // quarter 0..3
    int co = blockIdx.z * 128;
    int tid = threadIdx.x;
    int c4 = tid & 31;
    int es = tid >> 5;
    int j0 = 2 + qq * 250;
    int j1 = j0 + 250; if (j1 > Ss) j1 = Ss;
    const u16* yb = y + (size_t)b * Ss * M + co + c4 * 4;
    const float* dv = dinv + b * Ss;
    float a0 = 0.f, a1 = 0.f, a2 = 0.f, a3 = 0.f;
    for (int j = j0 + es; j < j1; j += 32) {
        float w = dv[j];
        float4 u = bf4(*(const ushort4*)(yb + (size_t)j * M));
        a0 += u.x * w; a1 += u.y * w; a2 += u.z * w; a3 += u.w * w;
    }
    __shared__ float4 red[1024];
    float4 mv; mv.x = a0; mv.y = a1; mv.z = a2; mv.w = a3;
    red[tid] = mv;
    __syncthreads();
#pragma unroll
    for (int s = 16; s > 0; s >>= 1) {
        if (es < s) {
            float4 o = red[tid + (s << 5)];
            float4 m = red[tid];
            m.x += o.x; m.y += o.y; m.z += o.z; m.w += o.w;
            red[tid] = m;
        }
        __syncthreads();
    }
    if (es == 0)
        *(float4*)(dq + ((size_t)qq * Bb + b) * M + co + c4 * 4) = red[c4];
}

// ---------- 8) aggregation M=512 + bias + relu -> single bf16 ----------
__global__ __launch_bounds__(128) void agg512_kernel(const u16* __restrict__ y,
                                                     const float* __restrict__ dinv,
                                                     const int* __restrict__ offs,
                                                     const int* __restrict__ indeg,
                                                     const u16* __restrict__ rev,
                                                     const float* __restrict__ bias,
                                                     const float* __restrict__ dep1,
                                                     u16* __restrict__ oX) {
    int bx = blockIdx.x;
    int x = bx & 7, q = bx >> 3;
    int bb = q / 1000;
    int i = q - bb * 1000;
    int b = x + (bb << 3);
    int n = b * Ss + i;
    int nb = n - i;
    int tid = threadIdx.x, c = tid * 4;

    __shared__ int   sidx[128];
    __shared__ float sw[128];
    int cnt = 0, o = 0;
    if (i >= 2) { cnt = indeg[n]; o = offs[n]; }
    int cl = cnt < 128 ? cnt : 128;
    if (tid < cl) {
        int s = rev[o + tid];
        sidx[tid] = s;
        sw[tid] = dinv[nb + s];
    }
    __syncthreads();

    float a0 = 0.f, a1 = 0.f, a2 = 0.f, a3 = 0.f;
    if (i >= 2) {
        float w = dinv[nb];  // == 1.0 (deg[0]=1)
        float4 v = bf4(*(const ushort4*)(y + (size_t)nb * 512 + c));
        a0 = v.x * w; a1 = v.y * w; a2 = v.z * w; a3 = v.w * w;
        int e = 0;
        for (; e + 4 <= cl; e += 4) {
            int s0 = sidx[e], s1 = sidx[e + 1], s2 = sidx[e + 2], s3 = sidx[e + 3];
            float w0 = sw[e], w1 = sw[e + 1], w2 = sw[e + 2], w3 = sw[e + 3];
            float4 u0 = bf4(*(const ushort4*)(y + (size_t)(nb + s0) * 512 + c));
            float4 u1 = bf4(*(const ushort4*)(y + (size_t)(nb + s1) * 512 + c));
            float4 u2 = bf4(*(const ushort4*)(y + (size_t)(nb + s2) * 512 + c));
            float4 u3 = bf4(*(const ushort4*)(y + (size_t)(nb + s3) * 512 + c));
            a0 += u0.x * w0 + u1.x * w1 + u2.x * w2 + u3.x * w3;
            a1 += u0.y * w0 + u1.y * w1 + u2.y * w2 + u3.y * w3;
            a2 += u0.z * w0 + u1.z * w1 + u2.z * w2 + u3.z * w3;
            a3 += u0.w * w0 + u1.w * w1 + u2.w * w2 + u3.w * w3;
        }
        for (; e < cl; ++e) {
            int s = sidx[e]; float ww = sw[e];
            float4 u = bf4(*(const ushort4*)(y + (size_t)(nb + s) * 512 + c));
            a0 += u.x * ww; a1 += u.y * ww; a2 += u.z * ww; a3 += u.w * ww;
        }
        for (int e2 = 128; e2 < cnt; ++e2) {   // safety fallback (never in practice)
            int s = rev[o + e2]; float ww = dinv[nb + s];
            float4 u = bf4(*(const ushort4*)(y + (size_t)(nb + s) * 512 + c));
            a0 += u.x * ww; a1 += u.y * ww; a2 += u.z * ww; a3 += u.w * ww;
        }
    } else if (i == 1) {
        const float* dp = dep1 + (size_t)b * 512 + c;
#pragma unroll
        for (int qq = 0; qq < 4; ++qq) {
            float4 v = *(const float4*)(dp + (size_t)qq * Bb * 512);
            a0 += v.x; a1 += v.y; a2 += v.z; a3 += v.w;
        }
    }
    float dn = dinv[n], sn = dn * dn;
    float4 vs = bf4(*(const ushort4*)(y + (size_t)n * 512 + c));
    float z0 = a0 * dn + vs.x * sn + bias[c];
    float z1 = a1 * dn + vs.y * sn + bias[c + 1];
    float z2 = a2 * dn + vs.z * sn + bias[c + 2];
    float z3 = a3 * dn + vs.w * sn + bias[c + 3];
    ushort4 hv;
    hv.x = f2bf(fmaxf(z0, 0.f));
    hv.y = f2bf(fmaxf(z1, 0.f));
    hv.z = f2bf(fmaxf(z2, 0.f));
    hv.w = f2bf(fmaxf(z3, 0.f));
    *(ushort4*)(oX + (size_t)n * 512 + c) = hv;
}

// ---------- 9) final aggregation M=128, no relu, fp32 out ----------
__global__ __launch_bounds__(128) void agg128f_kernel(const u16* __restrict__ y,
                                                      const float* __restrict__ dinv,
                                                      const int* __restrict__ offs,
                                                      const int* __restrict__ indeg,
                                                      const u16* __restrict__ rev,
                                                      const float* __restrict__ bias,
                                                      const float* __restrict__ dep1,
                                                      float* __restrict__ out) {
    int bx = blockIdx.x;
    int x = bx & 7, q = bx >> 3;
    int bb = q / 1000;
    int i = q - bb * 1000;
    int b = x + (bb << 3);
    int n = b * Ss + i;
    int nb = n - i;
    int tid = threadIdx.x, c = tid;

    __shared__ int   sidx[128];
    __shared__ float sw[128];
    int cnt = 0, o = 0;
    if (i >= 2) { cnt = indeg[n]; o = offs[n]; }
    int cl = cnt < 128 ? cnt : 128;
    if (tid < cl) {
        int s = rev[o + tid];
        sidx[tid] = s;
        sw[tid] = dinv[nb + s];
    }
    __syncthreads();

    float a = 0.f;
    if (i >= 2) {
        a = bf2f(y[(size_t)nb * 128 + c]) * dinv[nb];
        int e = 0;
        for (; e + 4 <= cl; e += 4) {
            int s0 = sidx[e], s1 = sidx[e + 1], s2 = sidx[e + 2], s3 = sidx[e + 3];
            float w0 = sw[e], w1 = sw[e + 1], w2 = sw[e + 2], w3 = sw[e + 3];
            float u0 = bf2f(y[(size_t)(nb + s0) * 128 + c]);
            float u1 = bf2f(y[(size_t)(nb + s1) * 128 + c]);
            float u2 = bf2f(y[(size_t)(nb + s2) * 128 + c]);
            float u3 = bf2f(y[(size_t)(nb + s3) * 128 + c]);
            a += u0 * w0 + u1 * w1 + u2 * w2 + u3 * w3;
        }
        for (; e < cl; ++e) a += bf2f(y[(size_t)(nb + sidx[e]) * 128 + c]) * sw[e];
        for (int e2 = 128; e2 < cnt; ++e2) {
            int s = rev[o + e2];
            a += bf2f(y[(size_t)(nb + s) * 128 + c]) * dinv[nb + s];
        }
    } else if (i == 1) {
#pragma unroll
        for (int qq = 0; qq < 4; ++qq)
            a += dep1[((size_t)qq * Bb + b) * 128 + c];
    }
    float dn = dinv[n];
    out[(size_t)n * 128 + c] = a * dn + bf2f(y[(size_t)n * 128 + c]) * (dn * dn) + bias[c];
}

// ---------- workspace layout (bytes); total ~134.9 MB ----------
constexpr size_t O_INDEG  = 0;                       // 256000
constexpr size_t O_CURSOR = 256000;                  // 256000
constexpr size_t O_OFFS   = 512000;                  // 256016
constexpr size_t O_DINV   = 768256;                  // 256000
constexpr size_t O_KNN    = 1024256;                 // 893824
constexpr size_t O_REV    = 1918080;                 // 893824
constexpr size_t O_AMAT   = 2811904;                 // 4*512*4 = 8192 (folded layer-0 wts)
constexpr size_t O_WT1    = 2942976;                 // 512*512*2 = 524288
constexpr size_t O_WT2    = 3467264;                 // 128*512*2 = 131072
constexpr size_t O_X      = 3598336;                 // 64000*512*2 = 65536000 (bf16 acts)
constexpr size_t O_Y      = 69134336;                // 65536000 (bf16 y)
constexpr size_t O_DEP1A  = 134670336;               // 4*64*512*4 = 524288
constexpr size_t O_DEP1B  = 135194624;               // 4*64*128*4 = 131072
constexpr size_t O_BSUM   = 135325696;               // 256

extern "C" void kernel_launch(void* const* d_in, const int* in_sizes, int n_in,
                              void* d_out, int out_size, void* d_ws, size_t ws_size,
                              hipStream_t stream) {
    const float* inputs = (const float*)d_in[0];
    const float* scor   = (const float*)d_in[1];
    const float* Wc     = (const float*)d_in[2];
    const float* bc     = (const float*)d_in[3];
    const float* Ws     = (const float*)d_in[4];
    const float* bs     = (const float*)d_in[5];
    const float* W0     = (const float*)d_in[6];
    const float* b0     = (const float*)d_in[7];
    const float* W1     = (const float*)d_in[8];
    const float* b1     = (const float*)d_in[9];
    const float* W2     = (const float*)d_in[10];
    const float* b2     = (const float*)d_in[11];

    char* w = (char*)d_ws;
    int*   indeg  = (int*)(w + O_INDEG);
    int*   cursor = (int*)(w + O_CURSOR);
    int*   offs   = (int*)(w + O_OFFS);
    float* dinv   = (float*)(w + O_DINV);
    u16*   knn    = (u16*)(w + O_KNN);
    u16*   rev    = (u16*)(w + O_REV);
    float* amat   = (float*)(w + O_AMAT);
    u16*   wt1    = (u16*)(w + O_WT1);
    u16*   wt2    = (u16*)(w + O_WT2);
    u16*   xbf    = (u16*)(w + O_X);
    u16*   ybf    = (u16*)(w + O_Y);
    float* dep1a  = (float*)(w + O_DEP1A);
    float* dep1b  = (float*)(w + O_DEP1B);
    int*   bsum   = (int*)(w + O_BSUM);

    hipMemsetAsync(w + O_INDEG, 0, 512000, stream);  // indeg + cursor

    knn_kernel<<<dim3(Bb, 32), 256, 0, stream>>>(inputs, knn, indeg);
    deg_dinv_kernel<<<250, 256, 0, stream>>>(indeg, dinv);
    scan1_kernel<<<63, 1024, 0, stream>>>(indeg, offs, bsum);
    scan2_kernel<<<1, 64, 0, stream>>>(bsum);
    scan3_kernel<<<63, 1024, 0, stream>>>(offs, bsum);
    fill_rev_kernel<<<dim3(Bb, 4), 256, 0, stream>>>(knn, offs, cursor, rev);

    fuse0_kernel<<<1, 512, 0, stream>>>(Wc, bc, Ws, bs, W0, amat);
    transp_kernel<<<(Hh * Hh + 255) / 256, 256, 0, stream>>>(W1, wt1, Hh, Hh);
    transp_kernel<<<(Hh * Dd + 255) / 256, 256, 0, stream>>>(W2, wt2, Hh, Dd);

    // layer 0: fused embed+gemm0 (rank-3 affine through 128-d bottleneck)
    gemm0f_kernel<<<NN * 128 / 256, 256, 0, stream>>>(inputs, scor, amat, ybf);
    dep1_kernel<<<dim3(Bb, 4, 4), 1024, 0, stream>>>(ybf, dinv, dep1a, Hh);
    agg512_kernel<<<NN, 128, 0, stream>>>(ybf, dinv, offs, indeg, rev, b0, dep1a, xbf);
    // layer 1: [N,512] @ [512,512]
    gemm_kernel<<<dim3(Hh / 128, NN / 128), 256, 0, stream>>>(xbf, wt1, ybf, Hh, Hh);
    dep1_kernel<<<dim3(Bb, 4, 4), 1024, 0, stream>>>(ybf, dinv, dep1a, Hh);
    agg512_kernel<<<NN, 128, 0, stream>>>(ybf, dinv, offs, indeg, rev, b1, dep1a, xbf);
    // layer 2: [N,512] @ [512,128]
    gemm_kernel<<<dim3(Dd / 128, NN / 128), 256, 0, stream>>>(xbf, wt2, ybf, Hh, Dd);
    dep1_kernel<<<dim3(Bb, 4, 1), 1024, 0, stream>>>(ybf, dinv, dep1b, Dd);
    agg128f_kernel<<<NN, 128, 0, stream>>>(ybf, dinv, offs, indeg, rev, b2, dep1b, (float*)d_out);
}